// Round 8
// baseline (865.255 us; speedup 1.0000x reference)
//
#include <hip/hip_runtime.h>
#include <hip/hip_bf16.h>

#define HID 128
#define NGRAPH 512
#define IN_DIM 384

typedef __attribute__((ext_vector_type(2))) float f32x2;
typedef __attribute__((ext_vector_type(4))) unsigned int u32x4;

// ---------------- degree ----------------
__global__ void deg_kernel(const int* __restrict__ dst, int* __restrict__ deg, int E) {
    int e = blockIdx.x * blockDim.x + threadIdx.x;
    if (e < E) atomicAdd(&deg[dst[e]], 1);
}

__global__ void dis_kernel(const int* __restrict__ deg, float* __restrict__ dis, int n) {
    int v = blockIdx.x * blockDim.x + threadIdx.x;
    if (v < n) dis[v] = rsqrtf((float)(deg[v] + 1));  // +1 = self-loop
}

// ---------------- exclusive scan of deg -> row_start ----------------
__global__ __launch_bounds__(256) void scan_part(const int* __restrict__ deg, int* __restrict__ row,
                                                 int* __restrict__ blockSums, int n) {
    __shared__ int ts[256];
    const int b = blockIdx.x, t = threadIdx.x;
    const int base = b * 1024 + t * 4;
    int v0 = (base + 0 < n) ? deg[base + 0] : 0;
    int v1 = (base + 1 < n) ? deg[base + 1] : 0;
    int v2 = (base + 2 < n) ? deg[base + 2] : 0;
    int v3 = (base + 3 < n) ? deg[base + 3] : 0;
    const int s = v0 + v1 + v2 + v3;
    ts[t] = s;
    __syncthreads();
    for (int off = 1; off < 256; off <<= 1) {
        int x = (t >= off) ? ts[t - off] : 0;
        __syncthreads();
        ts[t] += x;
        __syncthreads();
    }
    int p = ts[t] - s;
    if (base + 0 < n) { row[base + 0] = p; p += v0; }
    if (base + 1 < n) { row[base + 1] = p; p += v1; }
    if (base + 2 < n) { row[base + 2] = p; p += v2; }
    if (base + 3 < n) { row[base + 3] = p; }
    if (t == 255) blockSums[b] = ts[255];
}

__global__ void scan_tops(int* __restrict__ blockSums, int nb) {
    if (threadIdx.x == 0 && blockIdx.x == 0) {
        int acc = 0;
        for (int i = 0; i < nb; i++) { int v = blockSums[i]; blockSums[i] = acc; acc += v; }
    }
}

__global__ __launch_bounds__(256) void scan_add(int* __restrict__ row, int* __restrict__ cursor,
                                                const int* __restrict__ blockSums, int n, int E) {
    const int b = blockIdx.x, t = threadIdx.x;
    const int off = blockSums[b];
    const int base = b * 1024 + t * 4;
#pragma unroll
    for (int j = 0; j < 4; j++) {
        int i = base + j;
        if (i < n) { int v = row[i] + off; row[i] = v; cursor[i] = v; }
    }
    if (b == 0 && t == 0) row[n] = E;
}

// ---------------- CSR fill ----------------
__global__ void fill_kernel(const int* __restrict__ src, const int* __restrict__ dst,
                            int* __restrict__ cursor, int* __restrict__ csr_src, int E) {
    int e = blockIdx.x * blockDim.x + threadIdx.x;
    if (e < E) {
        int pos = atomicAdd(&cursor[dst[e]], 1);
        csr_src[pos] = src[e];
    }
}

// ---- tiled register-blocked GEMM: hs8[v,:] = fp8_e4m3( (X[v,:] @ W) * dis[v] * 8 ) ----
template <int K>
__global__ __launch_bounds__(256) void gemm_tile(const float* __restrict__ X,
                                                 const float* __restrict__ W,
                                                 const float* __restrict__ dis,
                                                 unsigned int* __restrict__ out8, int n) {
    constexpr int KC = 32;
    __shared__ float asT[KC][68];
    __shared__ float bs[KC * HID];
    const int t = threadIdx.x;
    const int tx = t & 31;   // col quad
    const int ty = t >> 5;   // row group
    const int row0 = blockIdx.x * 64;

    float4 acc[8];
#pragma unroll
    for (int j = 0; j < 8; j++) acc[j] = make_float4(0.f, 0.f, 0.f, 0.f);

    const int ar = t >> 3;
    const int af = t & 7;

    for (int k0 = 0; k0 < K; k0 += KC) {
#pragma unroll
        for (int half = 0; half < 2; half++) {
            const int r = ar + half * 32;
            const int gr = row0 + r;
            float4 a = make_float4(0.f, 0.f, 0.f, 0.f);
            if (gr < n) a = *(const float4*)&X[(long)gr * K + k0 + af * 4];
            asT[af * 4 + 0][r] = a.x;
            asT[af * 4 + 1][r] = a.y;
            asT[af * 4 + 2][r] = a.z;
            asT[af * 4 + 3][r] = a.w;
        }
        {
            const float4* wp = (const float4*)&W[(long)k0 * HID];
            float4* bp = (float4*)bs;
#pragma unroll
            for (int i = 0; i < 4; i++) bp[t + i * 256] = wp[t + i * 256];
        }
        __syncthreads();
#pragma unroll 8
        for (int kk = 0; kk < KC; kk++) {
            const float4 a0 = *(const float4*)&asT[kk][ty * 8];
            const float4 a1 = *(const float4*)&asT[kk][ty * 8 + 4];
            const float4 b  = *(const float4*)&bs[kk * HID + tx * 4];
            acc[0].x = fmaf(a0.x, b.x, acc[0].x); acc[0].y = fmaf(a0.x, b.y, acc[0].y);
            acc[0].z = fmaf(a0.x, b.z, acc[0].z); acc[0].w = fmaf(a0.x, b.w, acc[0].w);
            acc[1].x = fmaf(a0.y, b.x, acc[1].x); acc[1].y = fmaf(a0.y, b.y, acc[1].y);
            acc[1].z = fmaf(a0.y, b.z, acc[1].z); acc[1].w = fmaf(a0.y, b.w, acc[1].w);
            acc[2].x = fmaf(a0.z, b.x, acc[2].x); acc[2].y = fmaf(a0.z, b.y, acc[2].y);
            acc[2].z = fmaf(a0.z, b.z, acc[2].z); acc[2].w = fmaf(a0.z, b.w, acc[2].w);
            acc[3].x = fmaf(a0.w, b.x, acc[3].x); acc[3].y = fmaf(a0.w, b.y, acc[3].y);
            acc[3].z = fmaf(a0.w, b.z, acc[3].z); acc[3].w = fmaf(a0.w, b.w, acc[3].w);
            acc[4].x = fmaf(a1.x, b.x, acc[4].x); acc[4].y = fmaf(a1.x, b.y, acc[4].y);
            acc[4].z = fmaf(a1.x, b.z, acc[4].z); acc[4].w = fmaf(a1.x, b.w, acc[4].w);
            acc[5].x = fmaf(a1.y, b.x, acc[5].x); acc[5].y = fmaf(a1.y, b.y, acc[5].y);
            acc[5].z = fmaf(a1.y, b.z, acc[5].z); acc[5].w = fmaf(a1.y, b.w, acc[5].w);
            acc[6].x = fmaf(a1.z, b.x, acc[6].x); acc[6].y = fmaf(a1.z, b.y, acc[6].y);
            acc[6].z = fmaf(a1.z, b.z, acc[6].z); acc[6].w = fmaf(a1.z, b.w, acc[6].w);
            acc[7].x = fmaf(a1.w, b.x, acc[7].x); acc[7].y = fmaf(a1.w, b.y, acc[7].y);
            acc[7].z = fmaf(a1.w, b.z, acc[7].z); acc[7].w = fmaf(a1.w, b.w, acc[7].w);
        }
        __syncthreads();
    }

#pragma unroll
    for (int j = 0; j < 8; j++) {
        const int v = row0 + ty * 8 + j;
        if (v < n) {
            const float s = dis[v] * 8.0f;   // x8 keeps layer-2 messages out of e4m3 subnormals
            int w01 = __builtin_amdgcn_cvt_pk_fp8_f32(acc[j].x * s, acc[j].y * s, 0, false);
            int w   = __builtin_amdgcn_cvt_pk_fp8_f32(acc[j].z * s, acc[j].w * s, w01, true);
            out8[(long)v * (HID / 4) + tx] = (unsigned int)w;
        }
    }
}

// ---------------- gather aggregation, column-quarter pass ----------------
// Pass q handles fp8 cols [q*32, q*32+32): per-edge gather = 32 B; the active quarter
// table (50000 x 32 B = 1.6 MB) fits every XCD's 4 MB L2. One 64-lane wave per node;
// 2 lanes per edge (16 B each), 32 edges per gather instruction. Index loads and
// output stores are nontemporal so the streams don't evict the resident quarter.
template <bool POOL>
__global__ __launch_bounds__(256) void agg_kernel(const unsigned char* __restrict__ hs8,
                                                  const int* __restrict__ csr_src,
                                                  const int* __restrict__ row,
                                                  const float* __restrict__ dis,
                                                  const float* __restrict__ bias,
                                                  const int* __restrict__ batch,
                                                  float* __restrict__ out,
                                                  float* __restrict__ sums,
                                                  int* __restrict__ cnt, int n, int q) {
    const int v = blockIdx.x * 4 + (threadIdx.x >> 6);
    if (v >= n) return;
    const int lane = threadIdx.x & 63;
    const int esub = lane >> 1;          // edge slot within pass (0..31)
    const int lc   = lane & 1;           // 16-byte chunk within quarter
    const int boff = q * 32 + lc * 16;   // byte offset within row

    const int rs = row[v];
    const int re = row[v + 1];

    float acc[16];
#pragma unroll
    for (int i = 0; i < 16; i++) acc[i] = 0.f;

    for (int base = rs; base < re; base += 64) {
        u32x4 wv[2];
        int vld[2];
#pragma unroll
        for (int p = 0; p < 2; p++) {
            const int pe = base + p * 32;
            if (pe < re) {                       // wave-uniform guard
                const int ei = pe + esub;
                const int idx = __builtin_nontemporal_load(&csr_src[(ei < re) ? ei : (re - 1)]);
                wv[p] = *(const u32x4*)&hs8[(long)idx * HID + boff];
                vld[p] = (ei < re);
            } else {
                wv[p] = 0;
                vld[p] = 0;
            }
        }
#pragma unroll
        for (int p = 0; p < 2; p++) {
            if (vld[p]) {
                const u32x4 ww = wv[p];
                f32x2 u;
                u = __builtin_amdgcn_cvt_pk_f32_fp8(ww.x, false); acc[0]  += u.x; acc[1]  += u.y;
                u = __builtin_amdgcn_cvt_pk_f32_fp8(ww.x, true);  acc[2]  += u.x; acc[3]  += u.y;
                u = __builtin_amdgcn_cvt_pk_f32_fp8(ww.y, false); acc[4]  += u.x; acc[5]  += u.y;
                u = __builtin_amdgcn_cvt_pk_f32_fp8(ww.y, true);  acc[6]  += u.x; acc[7]  += u.y;
                u = __builtin_amdgcn_cvt_pk_f32_fp8(ww.z, false); acc[8]  += u.x; acc[9]  += u.y;
                u = __builtin_amdgcn_cvt_pk_f32_fp8(ww.z, true);  acc[10] += u.x; acc[11] += u.y;
                u = __builtin_amdgcn_cvt_pk_f32_fp8(ww.w, false); acc[12] += u.x; acc[13] += u.y;
                u = __builtin_amdgcn_cvt_pk_f32_fp8(ww.w, true);  acc[14] += u.x; acc[15] += u.y;
            }
        }
    }

    // fold the 32 edge-slot groups (lanes differing in bits 1..5, same lc)
#pragma unroll
    for (int i = 0; i < 16; i++) {
        acc[i] += __shfl_xor(acc[i], 2, 64);
        acc[i] += __shfl_xor(acc[i], 4, 64);
        acc[i] += __shfl_xor(acc[i], 8, 64);
        acc[i] += __shfl_xor(acc[i], 16, 64);
        acc[i] += __shfl_xor(acc[i], 32, 64);
    }

    // lanes 0..31 (esub<16) each own one column of this quarter
    if (esub < 16) {
        const int col = boff + esub;     // q*32 + lc*16 + esub
        const unsigned short sp = *(const unsigned short*)&hs8[(long)v * HID + (col & ~1)];
        f32x2 sf = __builtin_amdgcn_cvt_pk_f32_fp8((unsigned int)sp, false);
        const float self = (col & 1) ? sf.y : sf.x;
        const float sum = acc[esub] + self;
        const float dv = dis[v] * 0.125f;   // undo the x8 message scale
        const float r = fmaxf(fmaf(dv, sum, bias[col]), 0.f);
        if (POOL) {
            const int g = batch[v];
            unsafeAtomicAdd(&sums[g * HID + col], r);
            if (lane == 0 && q == 0) atomicAdd(&cnt[g], 1);
        } else {
            __builtin_nontemporal_store(r, &out[(long)v * HID + col]);
        }
    }
}

// ---------------- mean + MLP head ----------------
__global__ __launch_bounds__(64) void mlp_kernel(const float* __restrict__ sums,
                                                 const int* __restrict__ cnt,
                                                 const float* __restrict__ Wl1,
                                                 const float* __restrict__ bl1,
                                                 const float* __restrict__ Wl2,
                                                 const float* __restrict__ bl2,
                                                 float* __restrict__ out) {
    const int g = blockIdx.x, t = threadIdx.x;
    __shared__ float mean[HID];
    __shared__ float hid[64];
    const float c = fmaxf((float)cnt[g], 1.0f);
    mean[t] = sums[g * HID + t] / c;
    mean[t + 64] = sums[g * HID + 64 + t] / c;
    __syncthreads();
    float acc = bl1[t];
#pragma unroll 4
    for (int k = 0; k < HID; k++) acc = fmaf(mean[k], Wl1[k * 64 + t], acc);
    hid[t] = fmaxf(acc, 0.f);
    __syncthreads();
    if (t < 5) {
        float a = bl2[t];
#pragma unroll 4
        for (int k = 0; k < 64; k++) a = fmaf(hid[k], Wl2[k * 5 + t], a);
        out[g * 5 + t] = 1.f / (1.f + expf(-a));
    }
}

extern "C" void kernel_launch(void* const* d_in, const int* in_sizes, int n_in,
                              void* d_out, int out_size, void* d_ws, size_t ws_size,
                              hipStream_t stream) {
    const float* x   = (const float*)d_in[0];
    const int* ei    = (const int*)d_in[1];
    const int* batch = (const int*)d_in[2];
    const float* W1  = (const float*)d_in[3];
    const float* b1  = (const float*)d_in[4];
    const float* W2  = (const float*)d_in[5];
    const float* b2  = (const float*)d_in[6];
    const float* Wl1 = (const float*)d_in[7];
    const float* bl1 = (const float*)d_in[8];
    const float* Wl2 = (const float*)d_in[9];
    const float* bl2 = (const float*)d_in[10];
    float* out = (float*)d_out;

    const int n = in_sizes[0] / IN_DIM;       // 50000
    const int E = in_sizes[1] / 2;            // 1600000
    const int* src = ei;
    const int* dst = ei + E;

    char* ws = (char*)d_ws;
    size_t off = 0;
    auto alloc = [&](size_t bytes) {
        void* p = ws + off;
        off = (off + bytes + 255) & ~(size_t)255;
        return p;
    };
    int*   deg       = (int*)alloc((size_t)n * 4);
    float* dis       = (float*)alloc((size_t)n * 4);
    int*   row       = (int*)alloc((size_t)(n + 1) * 4);
    int*   cursor    = (int*)alloc((size_t)n * 4);
    int*   csr_src   = (int*)alloc((size_t)E * 4);
    int*   blockSums = (int*)alloc(256 * 4);
    unsigned char* hs8 = (unsigned char*)alloc((size_t)n * HID);       // fp8 messages
    float* buf1 = (float*)alloc((size_t)n * HID * 4);                  // fp32 inter-layer h
    float* sums = (float*)alloc((size_t)NGRAPH * HID * 4);
    int*   cnt  = (int*)alloc((size_t)NGRAPH * 4);
    (void)ws_size;

    const int nb = (n + 1023) / 1024;
    const int gemmBlocks = (n + 63) / 64;
    const int aggBlocks  = (n + 3) / 4;

    // --- degree / norm / CSR ---
    hipMemsetAsync(deg, 0, (size_t)n * 4, stream);
    deg_kernel<<<(E + 255) / 256, 256, 0, stream>>>(dst, deg, E);
    dis_kernel<<<(n + 255) / 256, 256, 0, stream>>>(deg, dis, n);
    scan_part<<<nb, 256, 0, stream>>>(deg, row, blockSums, n);
    scan_tops<<<1, 64, 0, stream>>>(blockSums, nb);
    scan_add<<<nb, 256, 0, stream>>>(row, cursor, blockSums, n, E);
    fill_kernel<<<(E + 255) / 256, 256, 0, stream>>>(src, dst, cursor, csr_src, E);

    // --- conv1 ---
    gemm_tile<IN_DIM><<<gemmBlocks, 256, 0, stream>>>(x, W1, dis, (unsigned int*)hs8, n);
    for (int q = 0; q < 4; q++)
        agg_kernel<false><<<aggBlocks, 256, 0, stream>>>(hs8, csr_src, row, dis, b1, batch,
                                                         buf1, nullptr, nullptr, n, q);

    // --- conv2 (pool fused) ---
    gemm_tile<HID><<<gemmBlocks, 256, 0, stream>>>(buf1, W2, dis, (unsigned int*)hs8, n);
    hipMemsetAsync(sums, 0, (size_t)NGRAPH * HID * 4, stream);
    hipMemsetAsync(cnt, 0, (size_t)NGRAPH * 4, stream);
    for (int q = 0; q < 4; q++)
        agg_kernel<true><<<aggBlocks, 256, 0, stream>>>(hs8, csr_src, row, dis, b2, batch,
                                                        nullptr, sums, cnt, n, q);

    // --- head ---
    mlp_kernel<<<NGRAPH, 64, 0, stream>>>(sums, cnt, Wl1, bl1, Wl2, bl2, out);
}

// Round 10
// 655.509 us; speedup vs baseline: 1.3200x; 1.3200x over previous
//
#include <hip/hip_runtime.h>
#include <hip/hip_bf16.h>

#define HID 128
#define NGRAPH 512
#define IN_DIM 384

typedef __attribute__((ext_vector_type(2))) float f32x2;

// ---------------- degree (split by source half) ----------------
// deg2[v]   = #edges into v with src <  half
// deg2[n+v] = #edges into v with src >= half
__global__ void deg_kernel(const int* __restrict__ src, const int* __restrict__ dst,
                           int* __restrict__ deg2, int E, int n, int half) {
    int e = blockIdx.x * blockDim.x + threadIdx.x;
    if (e < E) {
        const int s = src[e], d = dst[e];
        atomicAdd(&deg2[d + ((s < half) ? 0 : n)], 1);
    }
}

__global__ void dis_kernel(const int* __restrict__ deg2, float* __restrict__ dis, int n) {
    int v = blockIdx.x * blockDim.x + threadIdx.x;
    if (v < n) dis[v] = rsqrtf((float)(deg2[v] + deg2[n + v] + 1));  // +1 = self-loop
}

// ---------------- exclusive scan of deg2 (2n entries) -> row2 ----------------
__global__ __launch_bounds__(256) void scan_part(const int* __restrict__ deg, int* __restrict__ row,
                                                 int* __restrict__ blockSums, int n) {
    __shared__ int ts[256];
    const int b = blockIdx.x, t = threadIdx.x;
    const int base = b * 1024 + t * 4;
    int v0 = (base + 0 < n) ? deg[base + 0] : 0;
    int v1 = (base + 1 < n) ? deg[base + 1] : 0;
    int v2 = (base + 2 < n) ? deg[base + 2] : 0;
    int v3 = (base + 3 < n) ? deg[base + 3] : 0;
    const int s = v0 + v1 + v2 + v3;
    ts[t] = s;
    __syncthreads();
    for (int off = 1; off < 256; off <<= 1) {
        int x = (t >= off) ? ts[t - off] : 0;
        __syncthreads();
        ts[t] += x;
        __syncthreads();
    }
    int p = ts[t] - s;
    if (base + 0 < n) { row[base + 0] = p; p += v0; }
    if (base + 1 < n) { row[base + 1] = p; p += v1; }
    if (base + 2 < n) { row[base + 2] = p; p += v2; }
    if (base + 3 < n) { row[base + 3] = p; }
    if (t == 255) blockSums[b] = ts[255];
}

__global__ void scan_tops(int* __restrict__ blockSums, int nb) {
    if (threadIdx.x == 0 && blockIdx.x == 0) {
        int acc = 0;
        for (int i = 0; i < nb; i++) { int v = blockSums[i]; blockSums[i] = acc; acc += v; }
    }
}

__global__ __launch_bounds__(256) void scan_add(int* __restrict__ row, int* __restrict__ cursor,
                                                const int* __restrict__ blockSums, int n, int E) {
    const int b = blockIdx.x, t = threadIdx.x;
    const int off = blockSums[b];
    const int base = b * 1024 + t * 4;
#pragma unroll
    for (int j = 0; j < 4; j++) {
        int i = base + j;
        if (i < n) { int v = row[i] + off; row[i] = v; cursor[i] = v; }
    }
    if (b == 0 && t == 0) row[n] = E;
}

// ---------------- CSR fill (ushort src ids, split by source half) ----------------
__global__ void fill_kernel(const int* __restrict__ src, const int* __restrict__ dst,
                            int* __restrict__ cursor, unsigned short* __restrict__ csr16,
                            int E, int n, int half) {
    int e = blockIdx.x * blockDim.x + threadIdx.x;
    if (e < E) {
        const int s = src[e], d = dst[e];
        int pos = atomicAdd(&cursor[d + ((s < half) ? 0 : n)], 1);
        csr16[pos] = (unsigned short)s;
    }
}

// ---- tiled register-blocked GEMM: hs8[v,:] = fp8_e4m3( (X[v,:] @ W) * dis[v] * 8 ) ----
template <int K>
__global__ __launch_bounds__(256) void gemm_tile(const float* __restrict__ X,
                                                 const float* __restrict__ W,
                                                 const float* __restrict__ dis,
                                                 unsigned int* __restrict__ out8, int n) {
    constexpr int KC = 32;
    __shared__ float asT[KC][68];
    __shared__ float bs[KC * HID];
    const int t = threadIdx.x;
    const int tx = t & 31;   // col quad
    const int ty = t >> 5;   // row group
    const int row0 = blockIdx.x * 64;

    float4 acc[8];
#pragma unroll
    for (int j = 0; j < 8; j++) acc[j] = make_float4(0.f, 0.f, 0.f, 0.f);

    const int ar = t >> 3;
    const int af = t & 7;

    for (int k0 = 0; k0 < K; k0 += KC) {
#pragma unroll
        for (int half = 0; half < 2; half++) {
            const int r = ar + half * 32;
            const int gr = row0 + r;
            float4 a = make_float4(0.f, 0.f, 0.f, 0.f);
            if (gr < n) a = *(const float4*)&X[(long)gr * K + k0 + af * 4];
            asT[af * 4 + 0][r] = a.x;
            asT[af * 4 + 1][r] = a.y;
            asT[af * 4 + 2][r] = a.z;
            asT[af * 4 + 3][r] = a.w;
        }
        {
            const float4* wp = (const float4*)&W[(long)k0 * HID];
            float4* bp = (float4*)bs;
#pragma unroll
            for (int i = 0; i < 4; i++) bp[t + i * 256] = wp[t + i * 256];
        }
        __syncthreads();
#pragma unroll 8
        for (int kk = 0; kk < KC; kk++) {
            const float4 a0 = *(const float4*)&asT[kk][ty * 8];
            const float4 a1 = *(const float4*)&asT[kk][ty * 8 + 4];
            const float4 b  = *(const float4*)&bs[kk * HID + tx * 4];
            acc[0].x = fmaf(a0.x, b.x, acc[0].x); acc[0].y = fmaf(a0.x, b.y, acc[0].y);
            acc[0].z = fmaf(a0.x, b.z, acc[0].z); acc[0].w = fmaf(a0.x, b.w, acc[0].w);
            acc[1].x = fmaf(a0.y, b.x, acc[1].x); acc[1].y = fmaf(a0.y, b.y, acc[1].y);
            acc[1].z = fmaf(a0.y, b.z, acc[1].z); acc[1].w = fmaf(a0.y, b.w, acc[1].w);
            acc[2].x = fmaf(a0.z, b.x, acc[2].x); acc[2].y = fmaf(a0.z, b.y, acc[2].y);
            acc[2].z = fmaf(a0.z, b.z, acc[2].z); acc[2].w = fmaf(a0.z, b.w, acc[2].w);
            acc[3].x = fmaf(a0.w, b.x, acc[3].x); acc[3].y = fmaf(a0.w, b.y, acc[3].y);
            acc[3].z = fmaf(a0.w, b.z, acc[3].z); acc[3].w = fmaf(a0.w, b.w, acc[3].w);
            acc[4].x = fmaf(a1.x, b.x, acc[4].x); acc[4].y = fmaf(a1.x, b.y, acc[4].y);
            acc[4].z = fmaf(a1.x, b.z, acc[4].z); acc[4].w = fmaf(a1.x, b.w, acc[4].w);
            acc[5].x = fmaf(a1.y, b.x, acc[5].x); acc[5].y = fmaf(a1.y, b.y, acc[5].y);
            acc[5].z = fmaf(a1.y, b.z, acc[5].z); acc[5].w = fmaf(a1.y, b.w, acc[5].w);
            acc[6].x = fmaf(a1.z, b.x, acc[6].x); acc[6].y = fmaf(a1.z, b.y, acc[6].y);
            acc[6].z = fmaf(a1.z, b.z, acc[6].z); acc[6].w = fmaf(a1.z, b.w, acc[6].w);
            acc[7].x = fmaf(a1.w, b.x, acc[7].x); acc[7].y = fmaf(a1.w, b.y, acc[7].y);
            acc[7].z = fmaf(a1.w, b.z, acc[7].z); acc[7].w = fmaf(a1.w, b.w, acc[7].w);
        }
        __syncthreads();
    }

#pragma unroll
    for (int j = 0; j < 8; j++) {
        const int v = row0 + ty * 8 + j;
        if (v < n) {
            const float s = dis[v] * 8.0f;   // x8 keeps layer-2 messages out of e4m3 subnormals
            int w01 = __builtin_amdgcn_cvt_pk_fp8_f32(acc[j].x * s, acc[j].y * s, 0, false);
            int w   = __builtin_amdgcn_cvt_pk_fp8_f32(acc[j].z * s, acc[j].w * s, w01, true);
            out8[(long)v * (HID / 4) + tx] = (unsigned int)w;
        }
    }
}

// ---------------- gather aggregation, source-half phase ----------------
// PHASE 0: gather edges with src in [0,half) — active table = 3.2 MB, L2-resident;
//          write raw fp32 partial sums to buf (nontemporal).
// PHASE 1: gather edges with src in [half,n), add partial + self-loop, finalize
//          (dis scale, bias, relu); POOL -> atomic pool, else in-place store to buf.
// One 64-lane wave per node; 8 lanes/edge x 16 B, 8 edges/pass, 4 passes unrolled.
template <int PHASE, bool POOL>
__global__ __launch_bounds__(256) void agg_kernel(const unsigned char* __restrict__ hs8,
                                                  const unsigned short* __restrict__ csr16,
                                                  const int* __restrict__ row2,
                                                  const float* __restrict__ dis,
                                                  const float* __restrict__ bias,
                                                  const int* __restrict__ batch,
                                                  float* __restrict__ buf,
                                                  float* __restrict__ sums,
                                                  int* __restrict__ cnt, int n) {
    const int v = blockIdx.x * 4 + (threadIdx.x >> 6);
    if (v >= n) return;
    const int lane = threadIdx.x & 63;
    const int sub = lane >> 3;      // edge slot within pass (0..7)
    const int lc  = lane & 7;       // 16-byte chunk within row

    const int rbase = (PHASE == 0) ? v : (n + v);
    const int rs = row2[rbase];
    const int re = row2[rbase + 1];

    float acc[16];
#pragma unroll
    for (int i = 0; i < 16; i++) acc[i] = 0.f;

    for (int base = rs; base < re; base += 32) {
        uint4 w[4];
        int vld[4];
#pragma unroll
        for (int p = 0; p < 4; p++) {
            const int pe = base + p * 8;
            if (pe < re) {                       // wave-uniform guard
                const int ei = pe + sub;
                const int idx = __builtin_nontemporal_load(&csr16[(ei < re) ? ei : (re - 1)]);
                w[p] = *(const uint4*)&hs8[(long)idx * HID + (lc << 4)];
                vld[p] = (ei < re);
            } else {
                w[p] = make_uint4(0u, 0u, 0u, 0u);
                vld[p] = 0;
            }
        }
#pragma unroll
        for (int p = 0; p < 4; p++) {
            if (vld[p]) {
                const uint4 ww = w[p];
                f32x2 u;
                u = __builtin_amdgcn_cvt_pk_f32_fp8(ww.x, false); acc[0]  += u.x; acc[1]  += u.y;
                u = __builtin_amdgcn_cvt_pk_f32_fp8(ww.x, true);  acc[2]  += u.x; acc[3]  += u.y;
                u = __builtin_amdgcn_cvt_pk_f32_fp8(ww.y, false); acc[4]  += u.x; acc[5]  += u.y;
                u = __builtin_amdgcn_cvt_pk_f32_fp8(ww.y, true);  acc[6]  += u.x; acc[7]  += u.y;
                u = __builtin_amdgcn_cvt_pk_f32_fp8(ww.z, false); acc[8]  += u.x; acc[9]  += u.y;
                u = __builtin_amdgcn_cvt_pk_f32_fp8(ww.z, true);  acc[10] += u.x; acc[11] += u.y;
                u = __builtin_amdgcn_cvt_pk_f32_fp8(ww.w, false); acc[12] += u.x; acc[13] += u.y;
                u = __builtin_amdgcn_cvt_pk_f32_fp8(ww.w, true);  acc[14] += u.x; acc[15] += u.y;
            }
        }
    }

    // fold the 8 sub-groups (lanes differing in bits 3..5, same lc)
#pragma unroll
    for (int i = 0; i < 16; i++) {
        acc[i] += __shfl_xor(acc[i], 8, 64);
        acc[i] += __shfl_xor(acc[i], 16, 64);
        acc[i] += __shfl_xor(acc[i], 32, 64);
    }

    // each lane owns cols col, col+1 where col = 16*lc + 2*sub
    const int col = (lc << 4) + (sub << 1);
    const float px = acc[(sub << 1) + 0];
    const float py = acc[(sub << 1) + 1];

    if (PHASE == 0) {
        f32x2 r; r.x = px; r.y = py;
        __builtin_nontemporal_store(r, (f32x2*)&buf[(long)v * HID + col]);
    } else {
        const float2 part = *(const float2*)&buf[(long)v * HID + col];
        const unsigned short selfw = *(const unsigned short*)&hs8[(long)v * HID + col];
        f32x2 sf = __builtin_amdgcn_cvt_pk_f32_fp8((unsigned int)selfw, false);
        const float sx = part.x + px + sf.x;
        const float sy = part.y + py + sf.y;
        const float dv = dis[v] * 0.125f;   // undo the x8 message scale
        const float rx = fmaxf(fmaf(dv, sx, bias[col]), 0.f);
        const float ry = fmaxf(fmaf(dv, sy, bias[col + 1]), 0.f);
        if (POOL) {
            const int g = batch[v];
            unsafeAtomicAdd(&sums[g * HID + col], rx);
            unsafeAtomicAdd(&sums[g * HID + col + 1], ry);
            if (lane == 0) atomicAdd(&cnt[g], 1);
        } else {
            float2 r; r.x = rx; r.y = ry;
            *(float2*)&buf[(long)v * HID + col] = r;   // in-place finalize
        }
    }
}

// ---------------- mean + MLP head ----------------
__global__ __launch_bounds__(64) void mlp_kernel(const float* __restrict__ sums,
                                                 const int* __restrict__ cnt,
                                                 const float* __restrict__ Wl1,
                                                 const float* __restrict__ bl1,
                                                 const float* __restrict__ Wl2,
                                                 const float* __restrict__ bl2,
                                                 float* __restrict__ out) {
    const int g = blockIdx.x, t = threadIdx.x;
    __shared__ float mean[HID];
    __shared__ float hid[64];
    const float c = fmaxf((float)cnt[g], 1.0f);
    mean[t] = sums[g * HID + t] / c;
    mean[t + 64] = sums[g * HID + 64 + t] / c;
    __syncthreads();
    float acc = bl1[t];
#pragma unroll 4
    for (int k = 0; k < HID; k++) acc = fmaf(mean[k], Wl1[k * 64 + t], acc);
    hid[t] = fmaxf(acc, 0.f);
    __syncthreads();
    if (t < 5) {
        float a = bl2[t];
#pragma unroll 4
        for (int k = 0; k < 64; k++) a = fmaf(hid[k], Wl2[k * 5 + t], a);
        out[g * 5 + t] = 1.f / (1.f + expf(-a));
    }
}

extern "C" void kernel_launch(void* const* d_in, const int* in_sizes, int n_in,
                              void* d_out, int out_size, void* d_ws, size_t ws_size,
                              hipStream_t stream) {
    const float* x   = (const float*)d_in[0];
    const int* ei    = (const int*)d_in[1];
    const int* batch = (const int*)d_in[2];
    const float* W1  = (const float*)d_in[3];
    const float* b1  = (const float*)d_in[4];
    const float* W2  = (const float*)d_in[5];
    const float* b2  = (const float*)d_in[6];
    const float* Wl1 = (const float*)d_in[7];
    const float* bl1 = (const float*)d_in[8];
    const float* Wl2 = (const float*)d_in[9];
    const float* bl2 = (const float*)d_in[10];
    float* out = (float*)d_out;

    const int n = in_sizes[0] / IN_DIM;       // 50000
    const int E = in_sizes[1] / 2;            // 1600000
    const int half = n / 2;                   // source-half split point
    const int* src = ei;
    const int* dst = ei + E;

    char* ws = (char*)d_ws;
    size_t off = 0;
    auto alloc = [&](size_t bytes) {
        void* p = ws + off;
        off = (off + bytes + 255) & ~(size_t)255;
        return p;
    };
    int*   deg2      = (int*)alloc((size_t)(2 * n) * 4);
    float* dis       = (float*)alloc((size_t)n * 4);
    int*   row2      = (int*)alloc((size_t)(2 * n + 1) * 4);
    int*   cursor    = (int*)alloc((size_t)(2 * n) * 4);
    unsigned short* csr16 = (unsigned short*)alloc((size_t)E * 2);
    int*   blockSums = (int*)alloc(256 * 4);
    unsigned char* hs8 = (unsigned char*)alloc((size_t)n * HID);       // fp8 messages
    float* buf1 = (float*)alloc((size_t)n * HID * 4);                  // partials -> fp32 h
    float* sums = (float*)alloc((size_t)NGRAPH * HID * 4);
    int*   cnt  = (int*)alloc((size_t)NGRAPH * 4);
    (void)ws_size;

    const int nb2 = (2 * n + 1023) / 1024;    // scan blocks over 2n entries
    const int gemmBlocks = (n + 63) / 64;
    const int aggBlocks  = (n + 3) / 4;

    // --- degree / norm / split CSR ---
    hipMemsetAsync(deg2, 0, (size_t)(2 * n) * 4, stream);
    deg_kernel<<<(E + 255) / 256, 256, 0, stream>>>(src, dst, deg2, E, n, half);
    dis_kernel<<<(n + 255) / 256, 256, 0, stream>>>(deg2, dis, n);
    scan_part<<<nb2, 256, 0, stream>>>(deg2, row2, blockSums, 2 * n);
    scan_tops<<<1, 64, 0, stream>>>(blockSums, nb2);
    scan_add<<<nb2, 256, 0, stream>>>(row2, cursor, blockSums, 2 * n, E);
    fill_kernel<<<(E + 255) / 256, 256, 0, stream>>>(src, dst, cursor, csr16, E, n, half);

    // --- conv1 ---
    gemm_tile<IN_DIM><<<gemmBlocks, 256, 0, stream>>>(x, W1, dis, (unsigned int*)hs8, n);
    agg_kernel<0, false><<<aggBlocks, 256, 0, stream>>>(hs8, csr16, row2, dis, b1, batch,
                                                        buf1, nullptr, nullptr, n);
    agg_kernel<1, false><<<aggBlocks, 256, 0, stream>>>(hs8, csr16, row2, dis, b1, batch,
                                                        buf1, nullptr, nullptr, n);

    // --- conv2 (pool fused into phase 1) ---
    gemm_tile<HID><<<gemmBlocks, 256, 0, stream>>>(buf1, W2, dis, (unsigned int*)hs8, n);
    hipMemsetAsync(sums, 0, (size_t)NGRAPH * HID * 4, stream);
    hipMemsetAsync(cnt, 0, (size_t)NGRAPH * 4, stream);
    agg_kernel<0, false><<<aggBlocks, 256, 0, stream>>>(hs8, csr16, row2, dis, b2, batch,
                                                        buf1, nullptr, nullptr, n);
    agg_kernel<1, true><<<aggBlocks, 256, 0, stream>>>(hs8, csr16, row2, dis, b2, batch,
                                                       buf1, sums, cnt, n);

    // --- head ---
    mlp_kernel<<<NGRAPH, 64, 0, stream>>>(sums, cnt, Wl1, bl1, Wl2, bl2, out);
}

// Round 11
// 646.976 us; speedup vs baseline: 1.3374x; 1.0132x over previous
//
#include <hip/hip_runtime.h>
#include <hip/hip_bf16.h>

#define HID 128
#define NGRAPH 512
#define IN_DIM 384

typedef __attribute__((ext_vector_type(2))) float f32x2;

// ---------------- degree (split by source half) ----------------
__global__ void deg_kernel(const int* __restrict__ src, const int* __restrict__ dst,
                           int* __restrict__ deg2, int E, int n, int half) {
    int e = blockIdx.x * blockDim.x + threadIdx.x;
    if (e < E) {
        const int s = src[e], d = dst[e];
        atomicAdd(&deg2[d + ((s < half) ? 0 : n)], 1);
    }
}

__global__ void dis_kernel(const int* __restrict__ deg2, float* __restrict__ dis, int n) {
    int v = blockIdx.x * blockDim.x + threadIdx.x;
    if (v < n) dis[v] = rsqrtf((float)(deg2[v] + deg2[n + v] + 1));  // +1 = self-loop
}

// ---------------- exclusive scan of deg2 (2n entries) -> row2 ----------------
__global__ __launch_bounds__(256) void scan_part(const int* __restrict__ deg, int* __restrict__ row,
                                                 int* __restrict__ blockSums, int n) {
    __shared__ int ts[256];
    const int b = blockIdx.x, t = threadIdx.x;
    const int base = b * 1024 + t * 4;
    int v0 = (base + 0 < n) ? deg[base + 0] : 0;
    int v1 = (base + 1 < n) ? deg[base + 1] : 0;
    int v2 = (base + 2 < n) ? deg[base + 2] : 0;
    int v3 = (base + 3 < n) ? deg[base + 3] : 0;
    const int s = v0 + v1 + v2 + v3;
    ts[t] = s;
    __syncthreads();
    for (int off = 1; off < 256; off <<= 1) {
        int x = (t >= off) ? ts[t - off] : 0;
        __syncthreads();
        ts[t] += x;
        __syncthreads();
    }
    int p = ts[t] - s;
    if (base + 0 < n) { row[base + 0] = p; p += v0; }
    if (base + 1 < n) { row[base + 1] = p; p += v1; }
    if (base + 2 < n) { row[base + 2] = p; p += v2; }
    if (base + 3 < n) { row[base + 3] = p; }
    if (t == 255) blockSums[b] = ts[255];
}

__global__ void scan_tops(int* __restrict__ blockSums, int nb) {
    if (threadIdx.x == 0 && blockIdx.x == 0) {
        int acc = 0;
        for (int i = 0; i < nb; i++) { int v = blockSums[i]; blockSums[i] = acc; acc += v; }
    }
}

__global__ __launch_bounds__(256) void scan_add(int* __restrict__ row, int* __restrict__ cursor,
                                                const int* __restrict__ blockSums, int n, int E) {
    const int b = blockIdx.x, t = threadIdx.x;
    const int off = blockSums[b];
    const int base = b * 1024 + t * 4;
#pragma unroll
    for (int j = 0; j < 4; j++) {
        int i = base + j;
        if (i < n) { int v = row[i] + off; row[i] = v; cursor[i] = v; }
    }
    if (b == 0 && t == 0) row[n] = E;
}

// ---------------- CSR fill (ushort src ids, dst-range sweep) ----------------
// Sweep handles only dst in [lo,hi): csr16 writes confine to two dense ~400 KB
// regions that stay L2-resident until fully written -> low writeback amplification.
__global__ void fill_kernel(const int* __restrict__ src, const int* __restrict__ dst,
                            int* __restrict__ cursor, unsigned short* __restrict__ csr16,
                            int E, int n, int half, int lo, int hi) {
    int e = blockIdx.x * blockDim.x + threadIdx.x;
    if (e < E) {
        const int d = dst[e];
        if (d >= lo && d < hi) {
            const int s = src[e];
            int pos = atomicAdd(&cursor[d + ((s < half) ? 0 : n)], 1);
            csr16[pos] = (unsigned short)s;
        }
    }
}

// ---- tiled register-blocked GEMM: hs8[v,:] = fp8_e4m3( (X[v,:] @ W) * dis[v] * 8 ) ----
template <int K>
__global__ __launch_bounds__(256) void gemm_tile(const float* __restrict__ X,
                                                 const float* __restrict__ W,
                                                 const float* __restrict__ dis,
                                                 unsigned int* __restrict__ out8, int n) {
    constexpr int KC = 32;
    __shared__ float asT[KC][68];
    __shared__ float bs[KC * HID];
    const int t = threadIdx.x;
    const int tx = t & 31;   // col quad
    const int ty = t >> 5;   // row group
    const int row0 = blockIdx.x * 64;

    float4 acc[8];
#pragma unroll
    for (int j = 0; j < 8; j++) acc[j] = make_float4(0.f, 0.f, 0.f, 0.f);

    const int ar = t >> 3;
    const int af = t & 7;

    for (int k0 = 0; k0 < K; k0 += KC) {
#pragma unroll
        for (int half = 0; half < 2; half++) {
            const int r = ar + half * 32;
            const int gr = row0 + r;
            float4 a = make_float4(0.f, 0.f, 0.f, 0.f);
            if (gr < n) a = *(const float4*)&X[(long)gr * K + k0 + af * 4];
            asT[af * 4 + 0][r] = a.x;
            asT[af * 4 + 1][r] = a.y;
            asT[af * 4 + 2][r] = a.z;
            asT[af * 4 + 3][r] = a.w;
        }
        {
            const float4* wp = (const float4*)&W[(long)k0 * HID];
            float4* bp = (float4*)bs;
#pragma unroll
            for (int i = 0; i < 4; i++) bp[t + i * 256] = wp[t + i * 256];
        }
        __syncthreads();
#pragma unroll 8
        for (int kk = 0; kk < KC; kk++) {
            const float4 a0 = *(const float4*)&asT[kk][ty * 8];
            const float4 a1 = *(const float4*)&asT[kk][ty * 8 + 4];
            const float4 b  = *(const float4*)&bs[kk * HID + tx * 4];
            acc[0].x = fmaf(a0.x, b.x, acc[0].x); acc[0].y = fmaf(a0.x, b.y, acc[0].y);
            acc[0].z = fmaf(a0.x, b.z, acc[0].z); acc[0].w = fmaf(a0.x, b.w, acc[0].w);
            acc[1].x = fmaf(a0.y, b.x, acc[1].x); acc[1].y = fmaf(a0.y, b.y, acc[1].y);
            acc[1].z = fmaf(a0.y, b.z, acc[1].z); acc[1].w = fmaf(a0.y, b.w, acc[1].w);
            acc[2].x = fmaf(a0.z, b.x, acc[2].x); acc[2].y = fmaf(a0.z, b.y, acc[2].y);
            acc[2].z = fmaf(a0.z, b.z, acc[2].z); acc[2].w = fmaf(a0.z, b.w, acc[2].w);
            acc[3].x = fmaf(a0.w, b.x, acc[3].x); acc[3].y = fmaf(a0.w, b.y, acc[3].y);
            acc[3].z = fmaf(a0.w, b.z, acc[3].z); acc[3].w = fmaf(a0.w, b.w, acc[3].w);
            acc[4].x = fmaf(a1.x, b.x, acc[4].x); acc[4].y = fmaf(a1.x, b.y, acc[4].y);
            acc[4].z = fmaf(a1.x, b.z, acc[4].z); acc[4].w = fmaf(a1.x, b.w, acc[4].w);
            acc[5].x = fmaf(a1.y, b.x, acc[5].x); acc[5].y = fmaf(a1.y, b.y, acc[5].y);
            acc[5].z = fmaf(a1.y, b.z, acc[5].z); acc[5].w = fmaf(a1.y, b.w, acc[5].w);
            acc[6].x = fmaf(a1.z, b.x, acc[6].x); acc[6].y = fmaf(a1.z, b.y, acc[6].y);
            acc[6].z = fmaf(a1.z, b.z, acc[6].z); acc[6].w = fmaf(a1.z, b.w, acc[6].w);
            acc[7].x = fmaf(a1.w, b.x, acc[7].x); acc[7].y = fmaf(a1.w, b.y, acc[7].y);
            acc[7].z = fmaf(a1.w, b.z, acc[7].z); acc[7].w = fmaf(a1.w, b.w, acc[7].w);
        }
        __syncthreads();
    }

#pragma unroll
    for (int j = 0; j < 8; j++) {
        const int v = row0 + ty * 8 + j;
        if (v < n) {
            const float s = dis[v] * 8.0f;   // x8 keeps layer-2 messages out of e4m3 subnormals
            int w01 = __builtin_amdgcn_cvt_pk_fp8_f32(acc[j].x * s, acc[j].y * s, 0, false);
            int w   = __builtin_amdgcn_cvt_pk_fp8_f32(acc[j].z * s, acc[j].w * s, w01, true);
            out8[(long)v * (HID / 4) + tx] = (unsigned int)w;
        }
    }
}

// ---------------- gather aggregation, source-half phase ----------------
// PHASE 0: gather low-half edges (3.2 MB table, L2-resident); nt-store fp32 partials.
// PHASE 1: gather high-half edges; nt-load partial, add self-loop, finalize.
//          ALL buf1 stream traffic is nontemporal so it can't evict the gather table.
template <int PHASE, bool POOL>
__global__ __launch_bounds__(256) void agg_kernel(const unsigned char* __restrict__ hs8,
                                                  const unsigned short* __restrict__ csr16,
                                                  const int* __restrict__ row2,
                                                  const float* __restrict__ dis,
                                                  const float* __restrict__ bias,
                                                  const int* __restrict__ batch,
                                                  float* __restrict__ buf,
                                                  float* __restrict__ sums,
                                                  int* __restrict__ cnt, int n) {
    const int v = blockIdx.x * 4 + (threadIdx.x >> 6);
    if (v >= n) return;
    const int lane = threadIdx.x & 63;
    const int sub = lane >> 3;      // edge slot within pass (0..7)
    const int lc  = lane & 7;       // 16-byte chunk within row

    const int rbase = (PHASE == 0) ? v : (n + v);
    const int rs = row2[rbase];
    const int re = row2[rbase + 1];

    float acc[16];
#pragma unroll
    for (int i = 0; i < 16; i++) acc[i] = 0.f;

    for (int base = rs; base < re; base += 32) {
        uint4 w[4];
        int vld[4];
#pragma unroll
        for (int p = 0; p < 4; p++) {
            const int pe = base + p * 8;
            if (pe < re) {                       // wave-uniform guard
                const int ei = pe + sub;
                const int idx = __builtin_nontemporal_load(&csr16[(ei < re) ? ei : (re - 1)]);
                w[p] = *(const uint4*)&hs8[(long)idx * HID + (lc << 4)];
                vld[p] = (ei < re);
            } else {
                w[p] = make_uint4(0u, 0u, 0u, 0u);
                vld[p] = 0;
            }
        }
#pragma unroll
        for (int p = 0; p < 4; p++) {
            if (vld[p]) {
                const uint4 ww = w[p];
                f32x2 u;
                u = __builtin_amdgcn_cvt_pk_f32_fp8(ww.x, false); acc[0]  += u.x; acc[1]  += u.y;
                u = __builtin_amdgcn_cvt_pk_f32_fp8(ww.x, true);  acc[2]  += u.x; acc[3]  += u.y;
                u = __builtin_amdgcn_cvt_pk_f32_fp8(ww.y, false); acc[4]  += u.x; acc[5]  += u.y;
                u = __builtin_amdgcn_cvt_pk_f32_fp8(ww.y, true);  acc[6]  += u.x; acc[7]  += u.y;
                u = __builtin_amdgcn_cvt_pk_f32_fp8(ww.z, false); acc[8]  += u.x; acc[9]  += u.y;
                u = __builtin_amdgcn_cvt_pk_f32_fp8(ww.z, true);  acc[10] += u.x; acc[11] += u.y;
                u = __builtin_amdgcn_cvt_pk_f32_fp8(ww.w, false); acc[12] += u.x; acc[13] += u.y;
                u = __builtin_amdgcn_cvt_pk_f32_fp8(ww.w, true);  acc[14] += u.x; acc[15] += u.y;
            }
        }
    }

    // fold the 8 sub-groups (lanes differing in bits 3..5, same lc)
#pragma unroll
    for (int i = 0; i < 16; i++) {
        acc[i] += __shfl_xor(acc[i], 8, 64);
        acc[i] += __shfl_xor(acc[i], 16, 64);
        acc[i] += __shfl_xor(acc[i], 32, 64);
    }

    // each lane owns cols col, col+1 where col = 16*lc + 2*sub
    const int col = (lc << 4) + (sub << 1);
    const float px = acc[(sub << 1) + 0];
    const float py = acc[(sub << 1) + 1];

    if (PHASE == 0) {
        f32x2 r; r.x = px; r.y = py;
        __builtin_nontemporal_store(r, (f32x2*)&buf[(long)v * HID + col]);
    } else {
        const f32x2 part = __builtin_nontemporal_load((const f32x2*)&buf[(long)v * HID + col]);
        const unsigned short selfw = *(const unsigned short*)&hs8[(long)v * HID + col];
        f32x2 sf = __builtin_amdgcn_cvt_pk_f32_fp8((unsigned int)selfw, false);
        const float sx = part.x + px + sf.x;
        const float sy = part.y + py + sf.y;
        const float dv = dis[v] * 0.125f;   // undo the x8 message scale
        const float rx = fmaxf(fmaf(dv, sx, bias[col]), 0.f);
        const float ry = fmaxf(fmaf(dv, sy, bias[col + 1]), 0.f);
        if (POOL) {
            const int g = batch[v];
            unsafeAtomicAdd(&sums[g * HID + col], rx);
            unsafeAtomicAdd(&sums[g * HID + col + 1], ry);
            if (lane == 0) atomicAdd(&cnt[g], 1);
        } else {
            f32x2 r; r.x = rx; r.y = ry;
            __builtin_nontemporal_store(r, (f32x2*)&buf[(long)v * HID + col]);  // in place
        }
    }
}

// ---------------- mean + MLP head ----------------
__global__ __launch_bounds__(64) void mlp_kernel(const float* __restrict__ sums,
                                                 const int* __restrict__ cnt,
                                                 const float* __restrict__ Wl1,
                                                 const float* __restrict__ bl1,
                                                 const float* __restrict__ Wl2,
                                                 const float* __restrict__ bl2,
                                                 float* __restrict__ out) {
    const int g = blockIdx.x, t = threadIdx.x;
    __shared__ float mean[HID];
    __shared__ float hid[64];
    const float c = fmaxf((float)cnt[g], 1.0f);
    mean[t] = sums[g * HID + t] / c;
    mean[t + 64] = sums[g * HID + 64 + t] / c;
    __syncthreads();
    float acc = bl1[t];
#pragma unroll 4
    for (int k = 0; k < HID; k++) acc = fmaf(mean[k], Wl1[k * 64 + t], acc);
    hid[t] = fmaxf(acc, 0.f);
    __syncthreads();
    if (t < 5) {
        float a = bl2[t];
#pragma unroll 4
        for (int k = 0; k < 64; k++) a = fmaf(hid[k], Wl2[k * 5 + t], a);
        out[g * 5 + t] = 1.f / (1.f + expf(-a));
    }
}

extern "C" void kernel_launch(void* const* d_in, const int* in_sizes, int n_in,
                              void* d_out, int out_size, void* d_ws, size_t ws_size,
                              hipStream_t stream) {
    const float* x   = (const float*)d_in[0];
    const int* ei    = (const int*)d_in[1];
    const int* batch = (const int*)d_in[2];
    const float* W1  = (const float*)d_in[3];
    const float* b1  = (const float*)d_in[4];
    const float* W2  = (const float*)d_in[5];
    const float* b2  = (const float*)d_in[6];
    const float* Wl1 = (const float*)d_in[7];
    const float* bl1 = (const float*)d_in[8];
    const float* Wl2 = (const float*)d_in[9];
    const float* bl2 = (const float*)d_in[10];
    float* out = (float*)d_out;

    const int n = in_sizes[0] / IN_DIM;       // 50000
    const int E = in_sizes[1] / 2;            // 1600000
    const int half = n / 2;                   // source-half split point
    const int* src = ei;
    const int* dst = ei + E;

    char* ws = (char*)d_ws;
    size_t off = 0;
    auto alloc = [&](size_t bytes) {
        void* p = ws + off;
        off = (off + bytes + 255) & ~(size_t)255;
        return p;
    };
    int*   deg2      = (int*)alloc((size_t)(2 * n) * 4);
    float* dis       = (float*)alloc((size_t)n * 4);
    int*   row2      = (int*)alloc((size_t)(2 * n + 1) * 4);
    int*   cursor    = (int*)alloc((size_t)(2 * n) * 4);
    unsigned short* csr16 = (unsigned short*)alloc((size_t)E * 2);
    int*   blockSums = (int*)alloc(256 * 4);
    unsigned char* hs8 = (unsigned char*)alloc((size_t)n * HID);       // fp8 messages
    float* buf1 = (float*)alloc((size_t)n * HID * 4);                  // partials -> fp32 h
    float* sums = (float*)alloc((size_t)NGRAPH * HID * 4);
    int*   cnt  = (int*)alloc((size_t)NGRAPH * 4);
    (void)ws_size;

    const int nb2 = (2 * n + 1023) / 1024;    // scan blocks over 2n entries
    const int gemmBlocks = (n + 63) / 64;
    const int aggBlocks  = (n + 3) / 4;
    const int edgeBlocks = (E + 255) / 256;

    // --- degree / norm / split CSR ---
    hipMemsetAsync(deg2, 0, (size_t)(2 * n) * 4, stream);
    deg_kernel<<<edgeBlocks, 256, 0, stream>>>(src, dst, deg2, E, n, half);
    dis_kernel<<<(n + 255) / 256, 256, 0, stream>>>(deg2, dis, n);
    scan_part<<<nb2, 256, 0, stream>>>(deg2, row2, blockSums, 2 * n);
    scan_tops<<<1, 64, 0, stream>>>(blockSums, nb2);
    scan_add<<<nb2, 256, 0, stream>>>(row2, cursor, blockSums, 2 * n, E);
    // 4 dst-range sweeps keep csr16 writes L2-resident (low writeback amplification)
    {
        const int step = (n + 3) / 4;
        for (int k = 0; k < 4; k++) {
            const int lo = k * step;
            const int hi = (k == 3) ? n : (lo + step);
            fill_kernel<<<edgeBlocks, 256, 0, stream>>>(src, dst, cursor, csr16, E, n, half, lo, hi);
        }
    }

    // --- conv1 ---
    gemm_tile<IN_DIM><<<gemmBlocks, 256, 0, stream>>>(x, W1, dis, (unsigned int*)hs8, n);
    agg_kernel<0, false><<<aggBlocks, 256, 0, stream>>>(hs8, csr16, row2, dis, b1, batch,
                                                        buf1, nullptr, nullptr, n);
    agg_kernel<1, false><<<aggBlocks, 256, 0, stream>>>(hs8, csr16, row2, dis, b1, batch,
                                                        buf1, nullptr, nullptr, n);

    // --- conv2 (pool fused into phase 1) ---
    gemm_tile<HID><<<gemmBlocks, 256, 0, stream>>>(buf1, W2, dis, (unsigned int*)hs8, n);
    hipMemsetAsync(sums, 0, (size_t)NGRAPH * HID * 4, stream);
    hipMemsetAsync(cnt, 0, (size_t)NGRAPH * 4, stream);
    agg_kernel<0, false><<<aggBlocks, 256, 0, stream>>>(hs8, csr16, row2, dis, b2, batch,
                                                        buf1, nullptr, nullptr, n);
    agg_kernel<1, true><<<aggBlocks, 256, 0, stream>>>(hs8, csr16, row2, dis, b2, batch,
                                                       buf1, sums, cnt, n);

    // --- head ---
    mlp_kernel<<<NGRAPH, 64, 0, stream>>>(sums, cnt, Wl1, bl1, Wl2, bl2, out);
}

// Round 12
// 578.750 us; speedup vs baseline: 1.4950x; 1.1179x over previous
//
#include <hip/hip_runtime.h>
#include <hip/hip_bf16.h>

#define HID 128
#define NGRAPH 512
#define IN_DIM 384

typedef __attribute__((ext_vector_type(2))) float f32x2;

// ---------------- degree ----------------
__global__ void deg_kernel(const int* __restrict__ dst, int* __restrict__ deg, int E) {
    int e = blockIdx.x * blockDim.x + threadIdx.x;
    if (e < E) atomicAdd(&deg[dst[e]], 1);
}

__global__ void dis_kernel(const int* __restrict__ deg, float* __restrict__ dis, int n) {
    int v = blockIdx.x * blockDim.x + threadIdx.x;
    if (v < n) dis[v] = rsqrtf((float)(deg[v] + 1));  // +1 = self-loop
}

// ---------------- exclusive scan of deg -> row_start ----------------
__global__ __launch_bounds__(256) void scan_part(const int* __restrict__ deg, int* __restrict__ row,
                                                 int* __restrict__ blockSums, int n) {
    __shared__ int ts[256];
    const int b = blockIdx.x, t = threadIdx.x;
    const int base = b * 1024 + t * 4;
    int v0 = (base + 0 < n) ? deg[base + 0] : 0;
    int v1 = (base + 1 < n) ? deg[base + 1] : 0;
    int v2 = (base + 2 < n) ? deg[base + 2] : 0;
    int v3 = (base + 3 < n) ? deg[base + 3] : 0;
    const int s = v0 + v1 + v2 + v3;
    ts[t] = s;
    __syncthreads();
    for (int off = 1; off < 256; off <<= 1) {
        int x = (t >= off) ? ts[t - off] : 0;
        __syncthreads();
        ts[t] += x;
        __syncthreads();
    }
    int p = ts[t] - s;
    if (base + 0 < n) { row[base + 0] = p; p += v0; }
    if (base + 1 < n) { row[base + 1] = p; p += v1; }
    if (base + 2 < n) { row[base + 2] = p; p += v2; }
    if (base + 3 < n) { row[base + 3] = p; }
    if (t == 255) blockSums[b] = ts[255];
}

__global__ void scan_tops(int* __restrict__ blockSums, int nb) {
    if (threadIdx.x == 0 && blockIdx.x == 0) {
        int acc = 0;
        for (int i = 0; i < nb; i++) { int v = blockSums[i]; blockSums[i] = acc; acc += v; }
    }
}

__global__ __launch_bounds__(256) void scan_add(int* __restrict__ row, int* __restrict__ cursor,
                                                const int* __restrict__ blockSums, int n, int E) {
    const int b = blockIdx.x, t = threadIdx.x;
    const int off = blockSums[b];
    const int base = b * 1024 + t * 4;
#pragma unroll
    for (int j = 0; j < 4; j++) {
        int i = base + j;
        if (i < n) { int v = row[i] + off; row[i] = v; cursor[i] = v; }
    }
    if (b == 0 && t == 0) row[n] = E;
}

// ---------------- CSR fill (ushort src ids, dst-range sweep) ----------------
// Sweep handles only dst in [lo,hi): csr16 writes confine to a dense ~800 KB
// region that stays L2-resident until fully written -> low writeback amplification.
__global__ void fill_kernel(const int* __restrict__ src, const int* __restrict__ dst,
                            int* __restrict__ cursor, unsigned short* __restrict__ csr16,
                            int E, int lo, int hi) {
    int e = blockIdx.x * blockDim.x + threadIdx.x;
    if (e < E) {
        const int d = dst[e];
        if (d >= lo && d < hi) {
            int pos = atomicAdd(&cursor[d], 1);
            csr16[pos] = (unsigned short)src[e];
        }
    }
}

// ---- tiled register-blocked GEMM: hs8[v,:] = fp8_e4m3( (X[v,:] @ W) * dis[v] * 8 ) ----
template <int K>
__global__ __launch_bounds__(256) void gemm_tile(const float* __restrict__ X,
                                                 const float* __restrict__ W,
                                                 const float* __restrict__ dis,
                                                 unsigned int* __restrict__ out8, int n) {
    constexpr int KC = 32;
    __shared__ float asT[KC][68];
    __shared__ float bs[KC * HID];
    const int t = threadIdx.x;
    const int tx = t & 31;   // col quad
    const int ty = t >> 5;   // row group
    const int row0 = blockIdx.x * 64;

    float4 acc[8];
#pragma unroll
    for (int j = 0; j < 8; j++) acc[j] = make_float4(0.f, 0.f, 0.f, 0.f);

    const int ar = t >> 3;
    const int af = t & 7;

    for (int k0 = 0; k0 < K; k0 += KC) {
#pragma unroll
        for (int half = 0; half < 2; half++) {
            const int r = ar + half * 32;
            const int gr = row0 + r;
            float4 a = make_float4(0.f, 0.f, 0.f, 0.f);
            if (gr < n) a = *(const float4*)&X[(long)gr * K + k0 + af * 4];
            asT[af * 4 + 0][r] = a.x;
            asT[af * 4 + 1][r] = a.y;
            asT[af * 4 + 2][r] = a.z;
            asT[af * 4 + 3][r] = a.w;
        }
        {
            const float4* wp = (const float4*)&W[(long)k0 * HID];
            float4* bp = (float4*)bs;
#pragma unroll
            for (int i = 0; i < 4; i++) bp[t + i * 256] = wp[t + i * 256];
        }
        __syncthreads();
#pragma unroll 8
        for (int kk = 0; kk < KC; kk++) {
            const float4 a0 = *(const float4*)&asT[kk][ty * 8];
            const float4 a1 = *(const float4*)&asT[kk][ty * 8 + 4];
            const float4 b  = *(const float4*)&bs[kk * HID + tx * 4];
            acc[0].x = fmaf(a0.x, b.x, acc[0].x); acc[0].y = fmaf(a0.x, b.y, acc[0].y);
            acc[0].z = fmaf(a0.x, b.z, acc[0].z); acc[0].w = fmaf(a0.x, b.w, acc[0].w);
            acc[1].x = fmaf(a0.y, b.x, acc[1].x); acc[1].y = fmaf(a0.y, b.y, acc[1].y);
            acc[1].z = fmaf(a0.y, b.z, acc[1].z); acc[1].w = fmaf(a0.y, b.w, acc[1].w);
            acc[2].x = fmaf(a0.z, b.x, acc[2].x); acc[2].y = fmaf(a0.z, b.y, acc[2].y);
            acc[2].z = fmaf(a0.z, b.z, acc[2].z); acc[2].w = fmaf(a0.z, b.w, acc[2].w);
            acc[3].x = fmaf(a0.w, b.x, acc[3].x); acc[3].y = fmaf(a0.w, b.y, acc[3].y);
            acc[3].z = fmaf(a0.w, b.z, acc[3].z); acc[3].w = fmaf(a0.w, b.w, acc[3].w);
            acc[4].x = fmaf(a1.x, b.x, acc[4].x); acc[4].y = fmaf(a1.x, b.y, acc[4].y);
            acc[4].z = fmaf(a1.x, b.z, acc[4].z); acc[4].w = fmaf(a1.x, b.w, acc[4].w);
            acc[5].x = fmaf(a1.y, b.x, acc[5].x); acc[5].y = fmaf(a1.y, b.y, acc[5].y);
            acc[5].z = fmaf(a1.y, b.z, acc[5].z); acc[5].w = fmaf(a1.y, b.w, acc[5].w);
            acc[6].x = fmaf(a1.z, b.x, acc[6].x); acc[6].y = fmaf(a1.z, b.y, acc[6].y);
            acc[6].z = fmaf(a1.z, b.z, acc[6].z); acc[6].w = fmaf(a1.z, b.w, acc[6].w);
            acc[7].x = fmaf(a1.w, b.x, acc[7].x); acc[7].y = fmaf(a1.w, b.y, acc[7].y);
            acc[7].z = fmaf(a1.w, b.z, acc[7].z); acc[7].w = fmaf(a1.w, b.w, acc[7].w);
        }
        __syncthreads();
    }

#pragma unroll
    for (int j = 0; j < 8; j++) {
        const int v = row0 + ty * 8 + j;
        if (v < n) {
            const float s = dis[v] * 8.0f;   // x8 keeps layer-2 messages out of e4m3 subnormals
            int w01 = __builtin_amdgcn_cvt_pk_fp8_f32(acc[j].x * s, acc[j].y * s, 0, false);
            int w   = __builtin_amdgcn_cvt_pk_fp8_f32(acc[j].z * s, acc[j].w * s, w01, true);
            out8[(long)v * (HID / 4) + tx] = (unsigned int)w;
        }
    }
}

// ---------------- gather aggregation + finalize (+ optional fused pool) ----------------
// Single pass per conv (best measured structure): one 64-lane wave per dst node;
// 8 lanes/edge x 16 B (fp8 row = 128 B = 1 line/edge), 8 edges/pass, 4 passes unrolled.
template <bool POOL>
__global__ __launch_bounds__(256) void agg_kernel(const unsigned char* __restrict__ hs8,
                                                  const unsigned short* __restrict__ csr16,
                                                  const int* __restrict__ row,
                                                  const float* __restrict__ dis,
                                                  const float* __restrict__ bias,
                                                  const int* __restrict__ batch,
                                                  float* __restrict__ buf,
                                                  float* __restrict__ sums,
                                                  int* __restrict__ cnt, int n) {
    const int v = blockIdx.x * 4 + (threadIdx.x >> 6);
    if (v >= n) return;
    const int lane = threadIdx.x & 63;
    const int sub = lane >> 3;      // edge slot within pass (0..7)
    const int lc  = lane & 7;       // 16-byte chunk within row

    const int rs = row[v];
    const int re = row[v + 1];

    float acc[16];
#pragma unroll
    for (int i = 0; i < 16; i++) acc[i] = 0.f;

    for (int base = rs; base < re; base += 32) {
        uint4 w[4];
        int vld[4];
#pragma unroll
        for (int p = 0; p < 4; p++) {
            const int pe = base + p * 8;
            if (pe < re) {                       // wave-uniform guard
                const int ei = pe + sub;
                const int idx = __builtin_nontemporal_load(&csr16[(ei < re) ? ei : (re - 1)]);
                w[p] = *(const uint4*)&hs8[(long)idx * HID + (lc << 4)];
                vld[p] = (ei < re);
            } else {
                w[p] = make_uint4(0u, 0u, 0u, 0u);
                vld[p] = 0;
            }
        }
#pragma unroll
        for (int p = 0; p < 4; p++) {
            if (vld[p]) {
                const uint4 ww = w[p];
                f32x2 u;
                u = __builtin_amdgcn_cvt_pk_f32_fp8(ww.x, false); acc[0]  += u.x; acc[1]  += u.y;
                u = __builtin_amdgcn_cvt_pk_f32_fp8(ww.x, true);  acc[2]  += u.x; acc[3]  += u.y;
                u = __builtin_amdgcn_cvt_pk_f32_fp8(ww.y, false); acc[4]  += u.x; acc[5]  += u.y;
                u = __builtin_amdgcn_cvt_pk_f32_fp8(ww.y, true);  acc[6]  += u.x; acc[7]  += u.y;
                u = __builtin_amdgcn_cvt_pk_f32_fp8(ww.z, false); acc[8]  += u.x; acc[9]  += u.y;
                u = __builtin_amdgcn_cvt_pk_f32_fp8(ww.z, true);  acc[10] += u.x; acc[11] += u.y;
                u = __builtin_amdgcn_cvt_pk_f32_fp8(ww.w, false); acc[12] += u.x; acc[13] += u.y;
                u = __builtin_amdgcn_cvt_pk_f32_fp8(ww.w, true);  acc[14] += u.x; acc[15] += u.y;
            }
        }
    }

    // fold the 8 sub-groups (lanes differing in bits 3..5, same lc)
#pragma unroll
    for (int i = 0; i < 16; i++) {
        acc[i] += __shfl_xor(acc[i], 8, 64);
        acc[i] += __shfl_xor(acc[i], 16, 64);
        acc[i] += __shfl_xor(acc[i], 32, 64);
    }

    // each lane owns cols col, col+1 where col = 16*lc + 2*sub
    const int col = (lc << 4) + (sub << 1);
    const unsigned short selfw = *(const unsigned short*)&hs8[(long)v * HID + col];
    f32x2 sf = __builtin_amdgcn_cvt_pk_f32_fp8((unsigned int)selfw, false);
    const float sx = acc[(sub << 1) + 0] + sf.x;
    const float sy = acc[(sub << 1) + 1] + sf.y;
    const float dv = dis[v] * 0.125f;   // undo the x8 message scale
    const float rx = fmaxf(fmaf(dv, sx, bias[col]), 0.f);
    const float ry = fmaxf(fmaf(dv, sy, bias[col + 1]), 0.f);
    if (POOL) {
        const int g = batch[v];
        unsafeAtomicAdd(&sums[g * HID + col], rx);
        unsafeAtomicAdd(&sums[g * HID + col + 1], ry);
        if (lane == 0) atomicAdd(&cnt[g], 1);
    } else {
        float2 r; r.x = rx; r.y = ry;
        *(float2*)&buf[(long)v * HID + col] = r;
    }
}

// ---------------- mean + MLP head ----------------
__global__ __launch_bounds__(64) void mlp_kernel(const float* __restrict__ sums,
                                                 const int* __restrict__ cnt,
                                                 const float* __restrict__ Wl1,
                                                 const float* __restrict__ bl1,
                                                 const float* __restrict__ Wl2,
                                                 const float* __restrict__ bl2,
                                                 float* __restrict__ out) {
    const int g = blockIdx.x, t = threadIdx.x;
    __shared__ float mean[HID];
    __shared__ float hid[64];
    const float c = fmaxf((float)cnt[g], 1.0f);
    mean[t] = sums[g * HID + t] / c;
    mean[t + 64] = sums[g * HID + 64 + t] / c;
    __syncthreads();
    float acc = bl1[t];
#pragma unroll 4
    for (int k = 0; k < HID; k++) acc = fmaf(mean[k], Wl1[k * 64 + t], acc);
    hid[t] = fmaxf(acc, 0.f);
    __syncthreads();
    if (t < 5) {
        float a = bl2[t];
#pragma unroll 4
        for (int k = 0; k < 64; k++) a = fmaf(hid[k], Wl2[k * 5 + t], a);
        out[g * 5 + t] = 1.f / (1.f + expf(-a));
    }
}

extern "C" void kernel_launch(void* const* d_in, const int* in_sizes, int n_in,
                              void* d_out, int out_size, void* d_ws, size_t ws_size,
                              hipStream_t stream) {
    const float* x   = (const float*)d_in[0];
    const int* ei    = (const int*)d_in[1];
    const int* batch = (const int*)d_in[2];
    const float* W1  = (const float*)d_in[3];
    const float* b1  = (const float*)d_in[4];
    const float* W2  = (const float*)d_in[5];
    const float* b2  = (const float*)d_in[6];
    const float* Wl1 = (const float*)d_in[7];
    const float* bl1 = (const float*)d_in[8];
    const float* Wl2 = (const float*)d_in[9];
    const float* bl2 = (const float*)d_in[10];
    float* out = (float*)d_out;

    const int n = in_sizes[0] / IN_DIM;       // 50000
    const int E = in_sizes[1] / 2;            // 1600000
    const int* src = ei;
    const int* dst = ei + E;

    char* ws = (char*)d_ws;
    size_t off = 0;
    auto alloc = [&](size_t bytes) {
        void* p = ws + off;
        off = (off + bytes + 255) & ~(size_t)255;
        return p;
    };
    int*   deg       = (int*)alloc((size_t)n * 4);
    float* dis       = (float*)alloc((size_t)n * 4);
    int*   row       = (int*)alloc((size_t)(n + 1) * 4);
    int*   cursor    = (int*)alloc((size_t)n * 4);
    unsigned short* csr16 = (unsigned short*)alloc((size_t)E * 2);
    int*   blockSums = (int*)alloc(256 * 4);
    unsigned char* hs8 = (unsigned char*)alloc((size_t)n * HID);       // fp8 messages
    float* buf1 = (float*)alloc((size_t)n * HID * 4);                  // fp32 inter-layer h
    float* sums = (float*)alloc((size_t)NGRAPH * HID * 4);
    int*   cnt  = (int*)alloc((size_t)NGRAPH * 4);
    (void)ws_size;

    const int nb = (n + 1023) / 1024;
    const int gemmBlocks = (n + 63) / 64;
    const int aggBlocks  = (n + 3) / 4;
    const int edgeBlocks = (E + 255) / 256;

    // --- degree / norm / CSR ---
    hipMemsetAsync(deg, 0, (size_t)n * 4, stream);
    deg_kernel<<<edgeBlocks, 256, 0, stream>>>(dst, deg, E);
    dis_kernel<<<(n + 255) / 256, 256, 0, stream>>>(deg, dis, n);
    scan_part<<<nb, 256, 0, stream>>>(deg, row, blockSums, n);
    scan_tops<<<1, 64, 0, stream>>>(blockSums, nb);
    scan_add<<<nb, 256, 0, stream>>>(row, cursor, blockSums, n, E);
    // 4 dst-range sweeps keep csr16 writes L2-resident (low writeback amplification)
    {
        const int step = (n + 3) / 4;
        for (int k = 0; k < 4; k++) {
            const int lo = k * step;
            const int hi = (k == 3) ? n : (lo + step);
            fill_kernel<<<edgeBlocks, 256, 0, stream>>>(src, dst, cursor, csr16, E, lo, hi);
        }
    }

    // --- conv1 ---
    gemm_tile<IN_DIM><<<gemmBlocks, 256, 0, stream>>>(x, W1, dis, (unsigned int*)hs8, n);
    agg_kernel<false><<<aggBlocks, 256, 0, stream>>>(hs8, csr16, row, dis, b1, batch,
                                                     buf1, nullptr, nullptr, n);

    // --- conv2 (pool fused) ---
    gemm_tile<HID><<<gemmBlocks, 256, 0, stream>>>(buf1, W2, dis, (unsigned int*)hs8, n);
    hipMemsetAsync(sums, 0, (size_t)NGRAPH * HID * 4, stream);
    hipMemsetAsync(cnt, 0, (size_t)NGRAPH * 4, stream);
    agg_kernel<true><<<aggBlocks, 256, 0, stream>>>(hs8, csr16, row, dis, b2, batch,
                                                    nullptr, sums, cnt, n);

    // --- head ---
    mlp_kernel<<<NGRAPH, 64, 0, stream>>>(sums, cnt, Wl1, bl1, Wl2, bl2, out);
}